// Round 12
// baseline (17.455 us; speedup 1.0000x reference)
//
#include <hip/hip_runtime.h>
#include <math.h>

#define BB   512
#define NBLK 64     // blocks; 8 waves each -> one wave per row
#define TPB  512

// Node 1: 64 blocks x 8 waves; wave w of block b owns row j = 8b+w.
// Lane owns 8 contiguous columns (2x float4 + 2x int4). Block folds its 8
// row results in LDS and writes ONE (sum, cnt) pair with plain stores --
// the kernel boundary is the (free) device-wide release/acquire, so no
// atomics, fences, counters, or spins (R3/R9/R10/R11 lessons: any in-kernel
// cross-block sync or leading graph node costs 3-9 us; a trailing node
// costs ~0.5 us).
__global__ __launch_bounds__(TPB) void tshl_row_kernel(
    const float* __restrict__ pdist, const int* __restrict__ target,
    float* __restrict__ part_sum, float* __restrict__ part_cnt)
{
    const int lane = threadIdx.x & 63;
    const int w    = threadIdx.x >> 6;
    const int j    = (blockIdx.x << 3) + w;

    const int base = lane << 3;
    const float4 p0 = *(const float4*)(pdist + j * BB + base);
    const float4 p1 = *(const float4*)(pdist + j * BB + base + 4);
    const int4   t0 = *(const int4*)(target + base);
    const int4   t1 = *(const int4*)(target + base + 4);
    const int myLab = target[j];

    const float d[8]   = {p0.x, p0.y, p0.z, p0.w, p1.x, p1.y, p1.z, p1.w};
    const int   lab[8] = {t0.x, t0.y, t0.z, t0.w, t1.x, t1.y, t1.z, t1.w};

    bool neg[8], pos[8];
    float lmax = -INFINITY, lmin = INFINITY;
    #pragma unroll
    for (int u = 0; u < 8; ++u) {
        neg[u] = (lab[u] != myLab);
        pos[u] = (!neg[u]) && (base + u != j);
        lmin = fminf(lmin, d[u]);
        if (neg[u]) lmax = fmaxf(lmax, d[u]);
    }
    #pragma unroll
    for (int m = 32; m; m >>= 1) {
        lmax = fmaxf(lmax, __shfl_xor(lmax, m));
        lmin = fminf(lmin, __shfl_xor(lmin, m));
    }
    // masked_maximum fallback: no unequal label in row -> row min.
    const float neg_in = (lmax == -INFINITY) ? lmin : lmax;

    // Per positive i: shn = min{d[k] : neg[k] && d[k] > d[i]}, else neg_in.
    // 4 positives per iteration: independent butterflies interleave (ILP),
    // contributions accumulated in ascending bit order (bitwise == serial).
    // Validated absmax 0.0 in R9/R10/R11.
    float psum = 0.0f;
    int   npos = 0;
    #pragma unroll
    for (int u = 0; u < 8; ++u) {
        unsigned long long bal = __ballot(pos[u]);
        npos += __popcll(bal);
        while (bal) {   // wave-uniform trip count
            const int  s0 = __builtin_ctzll(bal); bal &= bal - 1;
            const bool v1 = (bal != 0);
            const int  s1 = v1 ? __builtin_ctzll(bal) : s0; if (v1) bal &= bal - 1;
            const bool v2 = (bal != 0);
            const int  s2 = v2 ? __builtin_ctzll(bal) : s0; if (v2) bal &= bal - 1;
            const bool v3 = (bal != 0);
            const int  s3 = v3 ? __builtin_ctzll(bal) : s0; if (v3) bal &= bal - 1;

            const float dp0 = __shfl(d[u], s0);
            const float dp1 = __shfl(d[u], s1);
            const float dp2 = __shfl(d[u], s2);
            const float dp3 = __shfl(d[u], s3);

            float c0 = INFINITY, c1 = INFINITY, c2 = INFINITY, c3 = INFINITY;
            #pragma unroll
            for (int v = 0; v < 8; ++v) {
                if (neg[v]) {
                    const float dv = d[v];
                    if (dv > dp0) c0 = fminf(c0, dv);
                    if (dv > dp1) c1 = fminf(c1, dv);
                    if (dv > dp2) c2 = fminf(c2, dv);
                    if (dv > dp3) c3 = fminf(c3, dv);
                }
            }
            #pragma unroll
            for (int m = 32; m; m >>= 1) {
                c0 = fminf(c0, __shfl_xor(c0, m));
                c1 = fminf(c1, __shfl_xor(c1, m));
                c2 = fminf(c2, __shfl_xor(c2, m));
                c3 = fminf(c3, __shfl_xor(c3, m));
            }
            psum += fmaxf(1.0f + dp0 - ((c0 < INFINITY) ? c0 : neg_in), 0.0f);
            if (v1) psum += fmaxf(1.0f + dp1 - ((c1 < INFINITY) ? c1 : neg_in), 0.0f);
            if (v2) psum += fmaxf(1.0f + dp2 - ((c2 < INFINITY) ? c2 : neg_in), 0.0f);
            if (v3) psum += fmaxf(1.0f + dp3 - ((c3 < INFINITY) ? c3 : neg_in), 0.0f);
        }
    }

    // Block fold of 8 wave results (fixed order -> deterministic), one
    // plain-store pair per block.
    __shared__ float ssum[8], scnt[8];
    if (lane == 0) { ssum[w] = psum; scnt[w] = (float)npos; }
    __syncthreads();
    if (threadIdx.x == 0) {
        float bs = 0.0f, bc = 0.0f;
        #pragma unroll
        for (int e = 0; e < 8; ++e) { bs += ssum[e]; bc += scnt[e]; }
        part_sum[blockIdx.x] = bs;
        part_cnt[blockIdx.x] = bc;
    }
}

// Node 2: one wave; lane b loads block b's partial pair, butterfly, divide.
__global__ __launch_bounds__(64) void tshl_final_kernel(
    const float* __restrict__ part_sum, const float* __restrict__ part_cnt,
    float* __restrict__ out)
{
    const int lane = threadIdx.x;
    float s = part_sum[lane];
    float c = part_cnt[lane];
    #pragma unroll
    for (int m = 32; m; m >>= 1) {
        s += __shfl_xor(s, m);
        c += __shfl_xor(c, m);
    }
    if (lane == 0) out[0] = s / fmaxf(c, 1.0f);
}

extern "C" void kernel_launch(void* const* d_in, const int* in_sizes, int n_in,
                              void* d_out, int out_size, void* d_ws, size_t ws_size,
                              hipStream_t stream) {
    const float* pdist  = (const float*)d_in[0];
    const int*   target = (const int*)d_in[1];
    float* ws       = (float*)d_ws;
    float* part_sum = ws;          // [64]
    float* part_cnt = ws + NBLK;   // [64]
    float* out      = (float*)d_out;

    tshl_row_kernel<<<NBLK, TPB, 0, stream>>>(pdist, target, part_sum, part_cnt);
    tshl_final_kernel<<<1, 64, 0, stream>>>(part_sum, part_cnt, out);
}

// Round 13
// 13.183 us; speedup vs baseline: 1.3240x; 1.3240x over previous
//
#include <hip/hip_runtime.h>
#include <math.h>

#define BB 512

// 4 rows per 256-thread block, one wave per row. No LDS, no barriers.
// Lane owns 8 contiguous columns -> 2x float4 / 2x int4 vector loads.
// EXACT resubmission of the R4 kernel (measured 13.37 us) as a
// reproducibility probe for the launch-floor regime.
__global__ __launch_bounds__(256) void tshl_row_kernel(
    const float* __restrict__ pdist, const int* __restrict__ target,
    float* __restrict__ row_sum, float* __restrict__ row_cnt)
{
    const int lane = threadIdx.x & 63;
    const int w    = threadIdx.x >> 6;
    const int j    = (blockIdx.x << 2) + w;

    const int base = lane << 3;           // 8 columns per lane, contiguous
    const float4 p0 = *(const float4*)(pdist + j * BB + base);
    const float4 p1 = *(const float4*)(pdist + j * BB + base + 4);
    const int4   t0 = *(const int4*)(target + base);
    const int4   t1 = *(const int4*)(target + base + 4);
    const int myLab = target[j];

    const float d[8]   = {p0.x, p0.y, p0.z, p0.w, p1.x, p1.y, p1.z, p1.w};
    const int   lab[8] = {t0.x, t0.y, t0.z, t0.w, t1.x, t1.y, t1.z, t1.w};

    bool neg[8], pos[8];
    float lmax = -INFINITY, lmin = INFINITY;
    #pragma unroll
    for (int u = 0; u < 8; ++u) {
        neg[u] = (lab[u] != myLab);
        pos[u] = (!neg[u]) && (base + u != j);
        lmin = fminf(lmin, d[u]);
        if (neg[u]) lmax = fmaxf(lmax, d[u]);
    }
    #pragma unroll
    for (int m = 32; m; m >>= 1) {
        lmax = fmaxf(lmax, __shfl_xor(lmax, m));
        lmin = fminf(lmin, __shfl_xor(lmin, m));
    }
    // masked_maximum fallback: no unequal label in row -> row min.
    const float neg_in = (lmax == -INFINITY) ? lmin : lmax;

    // Per positive i: shn = min{d[k] : label[k]!=myLab && d[k] > d[i]},
    // fallback neg_in. Iterate positives via ballot/ctz (register-only).
    float psum = 0.0f;
    int   npos = 0;
    #pragma unroll
    for (int u = 0; u < 8; ++u) {
        unsigned long long bal = __ballot(pos[u]);
        npos += __popcll(bal);
        while (bal) {
            const int src = __builtin_ctzll(bal);
            bal &= bal - 1;
            const float dpos = __shfl(d[u], src);
            float c = INFINITY;
            #pragma unroll
            for (int v = 0; v < 8; ++v)
                if (neg[v] && d[v] > dpos) c = fminf(c, d[v]);
            #pragma unroll
            for (int m = 32; m; m >>= 1) c = fminf(c, __shfl_xor(c, m));
            const float shn = (c < INFINITY) ? c : neg_in;
            psum += fmaxf(1.0f + dpos - shn, 0.0f);
        }
    }

    if (lane == 0) {
        row_sum[j] = psum;
        row_cnt[j] = (float)npos;
    }
}

// Single-wave final reduce: out = sum / max(cnt, 1).
__global__ __launch_bounds__(64) void tshl_final_kernel(
    const float* __restrict__ row_sum, const float* __restrict__ row_cnt,
    float* __restrict__ out)
{
    const int lane = threadIdx.x;
    const int base = lane << 3;
    const float4 s0 = *(const float4*)(row_sum + base);
    const float4 s1 = *(const float4*)(row_sum + base + 4);
    const float4 c0 = *(const float4*)(row_cnt + base);
    const float4 c1 = *(const float4*)(row_cnt + base + 4);
    float s = ((s0.x + s0.y) + (s0.z + s0.w)) + ((s1.x + s1.y) + (s1.z + s1.w));
    float c = ((c0.x + c0.y) + (c0.z + c0.w)) + ((c1.x + c1.y) + (c1.z + c1.w));
    #pragma unroll
    for (int m = 32; m; m >>= 1) {
        s += __shfl_xor(s, m);
        c += __shfl_xor(c, m);
    }
    if (lane == 0) out[0] = s / fmaxf(c, 1.0f);
}

extern "C" void kernel_launch(void* const* d_in, const int* in_sizes, int n_in,
                              void* d_out, int out_size, void* d_ws, size_t ws_size,
                              hipStream_t stream) {
    const float* pdist  = (const float*)d_in[0];
    const int*   target = (const int*)d_in[1];
    float* ws      = (float*)d_ws;
    float* row_sum = ws;          // [512]
    float* row_cnt = ws + BB;     // [512]
    float* out     = (float*)d_out;

    tshl_row_kernel<<<BB / 4, 256, 0, stream>>>(pdist, target, row_sum, row_cnt);
    tshl_final_kernel<<<1, 64, 0, stream>>>(row_sum, row_cnt, out);
}